// Round 2
// baseline (303.411 us; speedup 1.0000x reference)
//
#include <hip/hip_runtime.h>
#include <hip/hip_cooperative_groups.h>
#include <math.h>

namespace cg = cooperative_groups;

// Problem constants
#define BB 32
#define TT 1024
#define DD 256
#define NBLK 1024
#define ROWS_PER_BLK 32    // 32768 rows / 1024 blocks (blocks never straddle b: 32 | 1024)
#define CHUNKS_PER_B 32    // 1024 blocks / 32 batches

// Analytic collapse (verified round 1):
//   out[b,t,d] = (t < len[b]) ? (1+W[b,d])*x[b,t,d] + (t==0 ? Bf[b,d] : 0) : 0
// where c = (sum_t x)/len, W = MLP_W(c), Bf = MLP_B(c), exact GELU.
__global__ __launch_bounds__(256, 4)
void fused_all(const float* __restrict__ x, const int* __restrict__ len,
               const float* __restrict__ Ww1_w, const float* __restrict__ Ww1_b,
               const float* __restrict__ Ww2_w, const float* __restrict__ Ww2_b,
               const float* __restrict__ Wb1_w, const float* __restrict__ Wb1_b,
               const float* __restrict__ Wb2_w, const float* __restrict__ Wb2_b,
               float* __restrict__ out,
               float* __restrict__ partial,   // ws: [1024][256]
               float* __restrict__ Wout,      // ws: [32][256]
               float* __restrict__ Bout)      // ws: [32][256]
{
    cg::grid_group grid = cg::this_grid();
    __shared__ float4 red[4][64];   // per-wave phase-1 partials (4 KB)
    __shared__ float  csh[DD];      // c[b] for this block's MLP
    __shared__ float  hsh[DD];      // hidden layer

    const int g    = blockIdx.x;
    const int tid  = threadIdx.x;
    const int wave = tid >> 6;
    const int lane = tid & 63;
    const int row0 = g * ROWS_PER_BLK;

    // ---------------- Phase 1: partial sums over this block's 32 rows --------
    {
        const float4* xr = (const float4*)(x + (size_t)(row0 + wave * 8) * DD);
        float4 s; s.x = 0.f; s.y = 0.f; s.z = 0.f; s.w = 0.f;
#pragma unroll
        for (int r = 0; r < 8; ++r) {
            float4 v = xr[(size_t)r * 64 + lane];
            s.x += v.x; s.y += v.y; s.z += v.z; s.w += v.w;
        }
        red[wave][lane] = s;
    }
    __syncthreads();
    if (tid < 64) {
        float4 a = red[0][tid], b = red[1][tid], c = red[2][tid], d = red[3][tid];
        float4 s;
        s.x = (a.x + b.x) + (c.x + d.x);
        s.y = (a.y + b.y) + (c.y + d.y);
        s.z = (a.z + b.z) + (c.z + d.z);
        s.w = (a.w + b.w) + (c.w + d.w);
        ((float4*)(partial + (size_t)g * DD))[tid] = s;
    }

    grid.sync();

    // ---------------- Phase 2: 64 blocks -> c[b], then MLP (mlp = g&1) -------
    if (g < 2 * BB) {
        const int b   = g >> 1;
        const int mlp = g & 1;
        {   // c[b][tid] = (sum over 32 chunk-partials) / len[b]
            float s = 0.f;
            const float* pp = partial + (size_t)(b * CHUNKS_PER_B) * DD + tid;
#pragma unroll
            for (int ch = 0; ch < CHUNKS_PER_B; ++ch) s += pp[(size_t)ch * DD];
            csh[tid] = s / (float)len[b];
        }
        __syncthreads();
        const float* w1 = mlp ? Wb1_w : Ww1_w;
        const float* b1 = mlp ? Wb1_b : Ww1_b;
        const float* w2 = mlp ? Wb2_w : Ww2_w;
        const float* b2 = mlp ? Wb2_b : Ww2_b;
        float* op       = mlp ? Bout  : Wout;
        {   // layer 1: thread j computes h[j] = gelu(c . w1[j] + b1[j])
            const float4* wr = (const float4*)(w1 + (size_t)tid * DD);
            const float4* cc = (const float4*)csh;
            float s = 0.f;
#pragma unroll 8
            for (int k = 0; k < 64; ++k) {
                float4 w = wr[k];
                float4 c4 = cc[k];   // lane-uniform LDS read -> broadcast, conflict-free
                s += w.x * c4.x + w.y * c4.y + w.z * c4.z + w.w * c4.w;
            }
            float v = s + b1[tid];
            hsh[tid] = 0.5f * v * (1.0f + erff(v * 0.70710678118654752440f));
        }
        __syncthreads();
        {   // layer 2: thread d computes op[b][d] = h . w2[d] + b2[d]
            const float4* wr = (const float4*)(w2 + (size_t)tid * DD);
            const float4* hh = (const float4*)hsh;
            float s = 0.f;
#pragma unroll 8
            for (int k = 0; k < 64; ++k) {
                float4 w = wr[k];
                float4 h4 = hh[k];
                s += w.x * h4.x + w.y * h4.y + w.z * h4.z + w.w * h4.w;
            }
            op[b * DD + tid] = s + b2[tid];
        }
    }

    grid.sync();

    // ---------------- Phase 3: apply ----------------------------------------
    {
        const int b = row0 >> 10;
        const int L = len[b];
        const float4 w4 = ((const float4*)(Wout + b * DD))[lane];
        const float4 b4 = ((const float4*)(Bout + b * DD))[lane];
#pragma unroll
        for (int r = 0; r < 8; ++r) {
            const int row = row0 + wave * 8 + r;
            const int t   = row & (TT - 1);
            const size_t base = (size_t)row * DD;
            float4 res;
            if (t >= L) {
                res.x = 0.f; res.y = 0.f; res.z = 0.f; res.w = 0.f;
            } else {
                float4 x4 = ((const float4*)(x + base))[lane];
                res.x = x4.x + w4.x * x4.x;
                res.y = x4.y + w4.y * x4.y;
                res.z = x4.z + w4.z * x4.z;
                res.w = x4.w + w4.w * x4.w;
                if (t == 0) { res.x += b4.x; res.y += b4.y; res.z += b4.z; res.w += b4.w; }
            }
            ((float4*)(out + base))[lane] = res;
        }
    }
}

// Workspace layout (floats): partial [1024][256] = 262144, Wout @262144 (8192),
// Bout @270336 (8192). Total 278528 floats = 1.06 MiB.
extern "C" void kernel_launch(void* const* d_in, const int* in_sizes, int n_in,
                              void* d_out, int out_size, void* d_ws, size_t ws_size,
                              hipStream_t stream) {
    const float* x     = (const float*)d_in[0];
    const int*   len   = (const int*)d_in[1];
    const float* Ww1_w = (const float*)d_in[2];
    const float* Ww1_b = (const float*)d_in[3];
    const float* Ww2_w = (const float*)d_in[4];
    const float* Ww2_b = (const float*)d_in[5];
    const float* Wb1_w = (const float*)d_in[6];
    const float* Wb1_b = (const float*)d_in[7];
    const float* Wb2_w = (const float*)d_in[8];
    const float* Wb2_b = (const float*)d_in[9];
    float* out = (float*)d_out;

    float* ws      = (float*)d_ws;
    float* partial = ws;
    float* Wout    = ws + 262144;
    float* Bout    = ws + 270336;

    void* args[] = {
        (void*)&x, (void*)&len,
        (void*)&Ww1_w, (void*)&Ww1_b, (void*)&Ww2_w, (void*)&Ww2_b,
        (void*)&Wb1_w, (void*)&Wb1_b, (void*)&Wb2_w, (void*)&Wb2_b,
        (void*)&out, (void*)&partial, (void*)&Wout, (void*)&Bout,
    };
    hipLaunchCooperativeKernel((const void*)fused_all, dim3(NBLK), dim3(256),
                               args, 0, stream);
}

// Round 3
// 119.684 us; speedup vs baseline: 2.5351x; 2.5351x over previous
//
#include <hip/hip_runtime.h>
#include <math.h>

// Problem constants
#define BB 32
#define TT 1024
#define DD 256
#define NBLK1 1024          // k_partial blocks; 32 rows each (never straddles b)
#define CHUNKS_PER_B 32     // 1024 / 32

// Analytic collapse (verified round 1):
//   out[b,t,d] = (t < len[b]) ? (1+W[b,d])*x[b,t,d] + (t==0 ? Bf[b,d] : 0) : 0
// where c = (sum_t x)/len, W = MLP_W(c), Bf = MLP_B(c), exact GELU.
// Cooperative grid.sync() measured ~100us/barrier on this part (R2) — use
// stream-ordered dispatches instead.

// ---------------------------------------------------------------------------
// K1: partial[g][d] = sum of 32 consecutive rows of x. 1024 blocks x 256 thr.
// Each wave sums 8 rows as float4; LDS combine across the 4 waves.
// ---------------------------------------------------------------------------
__global__ __launch_bounds__(256)
void k_partial(const float* __restrict__ x, float* __restrict__ partial) {
    __shared__ float4 red[4][64];
    const int g    = blockIdx.x;
    const int tid  = threadIdx.x;
    const int wave = tid >> 6;
    const int lane = tid & 63;
    const int row0 = g * 32;

    const float4* xr = (const float4*)(x + (size_t)(row0 + wave * 8) * DD);
    float4 s; s.x = 0.f; s.y = 0.f; s.z = 0.f; s.w = 0.f;
#pragma unroll
    for (int r = 0; r < 8; ++r) {
        float4 v = xr[(size_t)r * 64 + lane];
        s.x += v.x; s.y += v.y; s.z += v.z; s.w += v.w;
    }
    red[wave][lane] = s;
    __syncthreads();
    if (tid < 64) {
        float4 a = red[0][tid], b = red[1][tid], c = red[2][tid], d = red[3][tid];
        float4 o;
        o.x = (a.x + b.x) + (c.x + d.x);
        o.y = (a.y + b.y) + (c.y + d.y);
        o.z = (a.z + b.z) + (c.z + d.z);
        o.w = (a.w + b.w) + (c.w + d.w);
        ((float4*)(partial + (size_t)g * DD))[tid] = o;
    }
}

// ---------------------------------------------------------------------------
// K2: 64 blocks -> block (b, mlp): c[b] = sum(partial)/len, then 2-layer MLP
// with exact GELU, all in LDS. mlp0 -> Wout, mlp1 -> Bout.
// ---------------------------------------------------------------------------
__global__ __launch_bounds__(256)
void k_mlp(const float* __restrict__ partial, const int* __restrict__ len,
           const float* __restrict__ Ww1_w, const float* __restrict__ Ww1_b,
           const float* __restrict__ Ww2_w, const float* __restrict__ Ww2_b,
           const float* __restrict__ Wb1_w, const float* __restrict__ Wb1_b,
           const float* __restrict__ Wb2_w, const float* __restrict__ Wb2_b,
           float* __restrict__ Wout, float* __restrict__ Bout) {
    __shared__ float csh[DD];
    __shared__ float hsh[DD];
    const int tid = threadIdx.x;
    const int b   = blockIdx.x >> 1;
    const int mlp = blockIdx.x & 1;

    {   // c[b][tid]
        float s = 0.f;
        const float* pp = partial + (size_t)(b * CHUNKS_PER_B) * DD + tid;
#pragma unroll
        for (int ch = 0; ch < CHUNKS_PER_B; ++ch) s += pp[(size_t)ch * DD];
        csh[tid] = s / (float)len[b];
    }
    __syncthreads();
    const float* w1 = mlp ? Wb1_w : Ww1_w;
    const float* b1 = mlp ? Wb1_b : Ww1_b;
    const float* w2 = mlp ? Wb2_w : Ww2_w;
    const float* b2 = mlp ? Wb2_b : Ww2_b;
    float* op       = mlp ? Bout  : Wout;
    {   // layer 1: h[j] = gelu_exact(c . w1[j] + b1[j])
        const float4* wr = (const float4*)(w1 + (size_t)tid * DD);
        const float4* cc = (const float4*)csh;
        float s = 0.f;
#pragma unroll 8
        for (int k = 0; k < 64; ++k) {
            float4 w = wr[k];
            float4 c4 = cc[k];
            s += w.x * c4.x + w.y * c4.y + w.z * c4.z + w.w * c4.w;
        }
        float v = s + b1[tid];
        hsh[tid] = 0.5f * v * (1.0f + erff(v * 0.70710678118654752440f));
    }
    __syncthreads();
    {   // layer 2: op[b][d] = h . w2[d] + b2[d]
        const float4* wr = (const float4*)(w2 + (size_t)tid * DD);
        const float4* hh = (const float4*)hsh;
        float s = 0.f;
#pragma unroll 8
        for (int k = 0; k < 64; ++k) {
            float4 w = wr[k];
            float4 h4 = hh[k];
            s += w.x * h4.x + w.y * h4.y + w.z * h4.z + w.w * h4.w;
        }
        op[b * DD + tid] = s + b2[tid];
    }
}

// ---------------------------------------------------------------------------
// K3: out[b,t,d] = (t<L) ? (1+W[b,d])*x + (t==0 ? B[b,d] : 0) : 0
// 8192 blocks x 256 threads; one wave per row, float4 per lane.
// ---------------------------------------------------------------------------
__global__ __launch_bounds__(256)
void k_apply(const float* __restrict__ x, const int* __restrict__ len,
             const float* __restrict__ Wf, const float* __restrict__ Bf,
             float* __restrict__ out) {
    const int row  = blockIdx.x * 4 + (threadIdx.x >> 6);
    const int lane = threadIdx.x & 63;
    const int b = row >> 10;
    const int t = row & (TT - 1);
    const int L = len[b];
    const size_t base = (size_t)row * DD;
    float4* o4 = (float4*)(out + base);
    if (t >= L) {
        float4 z; z.x = 0.f; z.y = 0.f; z.z = 0.f; z.w = 0.f;
        o4[lane] = z;
        return;
    }
    float4 x4 = ((const float4*)(x + base))[lane];
    float4 w4 = ((const float4*)(Wf + b * DD))[lane];
    float4 r;
    r.x = x4.x + w4.x * x4.x;
    r.y = x4.y + w4.y * x4.y;
    r.z = x4.z + w4.z * x4.z;
    r.w = x4.w + w4.w * x4.w;
    if (t == 0) {
        float4 b4 = ((const float4*)(Bf + b * DD))[lane];
        r.x += b4.x; r.y += b4.y; r.z += b4.z; r.w += b4.w;
    }
    o4[lane] = r;
}

// Workspace (floats): partial [1024][256] = 262144, Wout @262144 (8192),
// Bout @270336 (8192).
extern "C" void kernel_launch(void* const* d_in, const int* in_sizes, int n_in,
                              void* d_out, int out_size, void* d_ws, size_t ws_size,
                              hipStream_t stream) {
    const float* x     = (const float*)d_in[0];
    const int*   len   = (const int*)d_in[1];
    const float* Ww1_w = (const float*)d_in[2];
    const float* Ww1_b = (const float*)d_in[3];
    const float* Ww2_w = (const float*)d_in[4];
    const float* Ww2_b = (const float*)d_in[5];
    const float* Wb1_w = (const float*)d_in[6];
    const float* Wb1_b = (const float*)d_in[7];
    const float* Wb2_w = (const float*)d_in[8];
    const float* Wb2_b = (const float*)d_in[9];
    float* out = (float*)d_out;

    float* ws      = (float*)d_ws;
    float* partial = ws;
    float* Wout    = ws + 262144;
    float* Bout    = ws + 270336;

    k_partial<<<NBLK1, 256, 0, stream>>>(x, partial);
    k_mlp<<<2 * BB, 256, 0, stream>>>(partial, len,
                                      Ww1_w, Ww1_b, Ww2_w, Ww2_b,
                                      Wb1_w, Wb1_b, Wb2_w, Wb2_b,
                                      Wout, Bout);
    k_apply<<<BB * TT / 4, 256, 0, stream>>>(x, len, Wout, Bout, out);
}